// Round 4
// baseline (161.606 us; speedup 1.0000x reference)
//
#include <hip/hip_runtime.h>
#include <math.h>

// ProtoLoss, MI355X (gfx950) — f16-split MFMA version.
//
// reference:  anchor = mean(x[:,1:,:],1); pos = x[:,0,:]
//   logit[i,j] = -dist2 = s[i,j] + K_i,  s = 2*pos_i.anc_j + b_j,
//   b_j = -|anc_j|^2 + 2e*sum(anc_j).   K_i cancels in log_softmax/argmax.
//   nloss = mean(lse_i - s_ii), prec1 = 100*mean(argmax_j s == i).
// fp32 GEMM emulated as one f16 GEMM with K=384: A = [hi(pos)|lo(pos)],
// B = [hi(anc)|lo(anc)]  (hi+lo carries ~22 mantissa bits; error ~1e-5 abs
// on logits of scale ~10 — far under argmax top-2 gaps ~2.0).

#define NROWS  8192
#define DDIM   192
#define KSPL   384            // hi|lo concatenated along K
#define X3     576
#define FEPS   1e-6f

#define BM 128
#define BN 128
#define BK 64
#define NSPLIT 8
#define JRANGE 1024           // NROWS / NSPLIT
#define JTILES 8              // JRANGE / BN
#define NPART  16             // NSPLIT * 2 (wn halves)
#define NCOMB  32             // combine-partial blocks

typedef _Float16 f16;
typedef _Float16 f16x8 __attribute__((ext_vector_type(8)));
typedef float    f32x4 __attribute__((ext_vector_type(4)));

__device__ __forceinline__ void async_copy16(const void* g, void* l) {
  __builtin_amdgcn_global_load_lds(
      (const __attribute__((address_space(1))) unsigned int*)g,
      (__attribute__((address_space(3))) unsigned int*)l, 16, 0, 0);
}

// ---------- Kernel 1: split x into (pos_hi|pos_lo), (anc_hi|anc_lo), bvec ----
__global__ __launch_bounds__(256) void prep_kernel(const float* __restrict__ x,
                                                   f16* __restrict__ ph,
                                                   f16* __restrict__ ah,
                                                   float* __restrict__ bvec) {
  int row  = (blockIdx.x * 256 + threadIdx.x) >> 6;
  int lane = threadIdx.x & 63;
  if (row >= NROWS) return;
  const float* xr = x + (size_t)row * X3;
  float an = 0.f, as = 0.f;
  #pragma unroll
  for (int t = 0; t < 3; ++t) {
    int d = lane + t * 64;
    float p = xr[d];
    float a = 0.5f * (xr[DDIM + d] + xr[2 * DDIM + d]);
    f16 phh = (f16)p;
    f16 pll = (f16)(p - (float)phh);
    ph[(size_t)row * KSPL + d] = phh;
    ph[(size_t)row * KSPL + DDIM + d] = pll;
    f16 ahh = (f16)a;
    f16 all = (f16)(a - (float)ahh);
    ah[(size_t)row * KSPL + d] = ahh;
    ah[(size_t)row * KSPL + DDIM + d] = all;
    an += a * a;
    as += a;
  }
  #pragma unroll
  for (int m = 32; m; m >>= 1) {
    an += __shfl_xor(an, m);
    as += __shfl_xor(as, m);
  }
  if (lane == 0) bvec[row] = -an + 2.0f * FEPS * as;
}

// ---------- Kernel 2: f16 MFMA GEMM (K=384) + fused online LSE/argmax -------
// grid (64, 8) = 512 blocks = exactly 2/CU (full single-round residency).
// block 256 = 4 waves as 2x2; wave = 64x64 via 4x4 frags of
// mfma_f32_16x16x32_f16.  LDS staged by global_load_lds (linear dest) with
// XOR-swizzled source; ds_read applies the same swizzle -> bank-optimal.
__global__ __launch_bounds__(256, 2) void main_kernel(
    const f16* __restrict__ Ag, const f16* __restrict__ Bg,
    const float* __restrict__ bvec,
    float* __restrict__ pm, float* __restrict__ ps, int* __restrict__ pa,
    float* __restrict__ diag) {
  __shared__ __align__(16) f16 As[BM * BK];   // 16 KB
  __shared__ __align__(16) f16 Bs[BN * BK];   // 16 KB
  const int tid  = threadIdx.x;
  const int lane = tid & 63;
  const int wid  = tid >> 6;
  const int wm = wid >> 1, wn = wid & 1;
  const int lLow = lane & 15, lHi = lane >> 4, l7 = lane & 7;
  const int i0 = blockIdx.x * BM;
  const int split = blockIdx.y;

  // staging geometry: chunk ci = q*4+wid covers LDS rows [ci*8, ci*8+8),
  // lane -> (row = ci*8 + lane>>3, slot = lane&7); source k-offset swizzled
  // so LDS[row][slot] holds global k-chunk (slot ^ (row&7)).
  const int rsub = lane >> 3;                       // row & 7
  const int srck = ((lane & 7) ^ rsub) * 8;         // swizzled k-chunk (elems)

  float mrun[16], srun[16];
  int   arun[16];
  #pragma unroll
  for (int r = 0; r < 16; ++r) { mrun[r] = -3.0e38f; srun[r] = 0.f; arun[r] = 0; }

  for (int jt = 0; jt < JTILES; ++jt) {
    const int j0 = split * JRANGE + jt * BN;
    f32x4 acc[4][4];
    #pragma unroll
    for (int mf = 0; mf < 4; ++mf)
      #pragma unroll
      for (int nf = 0; nf < 4; ++nf) acc[mf][nf] = (f32x4)0.f;

    for (int kc = 0; kc < KSPL; kc += BK) {
      __syncthreads();                      // previous tile fully consumed
      #pragma unroll
      for (int q = 0; q < 4; ++q) {
        const int ci  = q * 4 + wid;
        const int row = ci * 8 + rsub;
        async_copy16(Ag + (size_t)(i0 + row) * KSPL + kc + srck, (void*)(As + ci * 512));
        async_copy16(Bg + (size_t)(j0 + row) * KSPL + kc + srck, (void*)(Bs + ci * 512));
      }
      __syncthreads();                      // compiler drains vmcnt before barrier
      #pragma unroll
      for (int kk = 0; kk < 2; ++kk) {
        const int ksw = ((kk * 4 + lHi) ^ l7) * 8;  // swizzled read chunk
        f16x8 af[4];
        #pragma unroll
        for (int mf = 0; mf < 4; ++mf) {
          int r = wm * 64 + mf * 16 + lLow;
          af[mf] = *(const f16x8*)(As + r * 64 + ksw);
        }
        #pragma unroll
        for (int nf = 0; nf < 4; ++nf) {
          int r = wn * 64 + nf * 16 + lLow;
          f16x8 bf = *(const f16x8*)(Bs + r * 64 + ksw);
          #pragma unroll
          for (int mf = 0; mf < 4; ++mf)
            acc[mf][nf] = __builtin_amdgcn_mfma_f32_16x16x32_f16(af[mf], bf, acc[mf][nf], 0, 0, 0);
        }
      }
    }

    // ---- epilogue: fold this 128-wide j-tile into per-lane online state ----
    float bv[4];
    int   gc[4];
    #pragma unroll
    for (int nf = 0; nf < 4; ++nf) {
      gc[nf] = j0 + wn * 64 + nf * 16 + lLow;
      bv[nf] = bvec[gc[nf]];
    }
    // diagonal tile: j0 == i0  <=>  split*8 + jt == blockIdx.x
    const bool dtile = (split == (int)(blockIdx.x >> 3)) && (jt == (int)(blockIdx.x & 7));
    #pragma unroll
    for (int mf = 0; mf < 4; ++mf) {
      #pragma unroll
      for (int reg = 0; reg < 4; ++reg) {
        const int rs = mf * 4 + reg;
        const int grow = i0 + wm * 64 + mf * 16 + lHi * 4 + reg;
        float v0 = 2.f * acc[mf][0][reg] + bv[0];
        float v1 = 2.f * acc[mf][1][reg] + bv[1];
        float v2 = 2.f * acc[mf][2][reg] + bv[2];
        float v3 = 2.f * acc[mf][3][reg] + bv[3];
        if (dtile) {
          if (grow == gc[0]) diag[grow] = v0;
          if (grow == gc[1]) diag[grow] = v1;
          if (grow == gc[2]) diag[grow] = v2;
          if (grow == gc[3]) diag[grow] = v3;
        }
        float tm = v0; int tj = gc[0];                    // cols ascend with nf:
        if (v1 > tm) { tm = v1; tj = gc[1]; }             // strict > = first max
        if (v2 > tm) { tm = v2; tj = gc[2]; }
        if (v3 > tm) { tm = v3; tj = gc[3]; }
        float nm = fmaxf(tm, mrun[rs]);
        float se = __expf(v0 - nm) + __expf(v1 - nm) + __expf(v2 - nm) + __expf(v3 - nm);
        srun[rs] = srun[rs] * __expf(mrun[rs] - nm) + se;
        if (tm > mrun[rs]) arun[rs] = tj;                 // tie keeps earlier j
        mrun[rs] = nm;
      }
    }
  }

  // ---- reduce the 16 lanes sharing each row, write partials ----
  #pragma unroll
  for (int rs = 0; rs < 16; ++rs) {
    float mm = mrun[rs], ss = srun[rs];
    int aa = arun[rs];
    #pragma unroll
    for (int d = 1; d < 16; d <<= 1) {
      float om = __shfl_xor(mm, d, 16);
      float os = __shfl_xor(ss, d, 16);
      int   oa = __shfl_xor(aa, d, 16);
      float nm = fmaxf(mm, om);
      ss = ss * __expf(mm - nm) + os * __expf(om - nm);
      if (om > mm || (om == mm && oa < aa)) aa = oa;      // min-j on ties
      mm = nm;
    }
    if (lLow == 0) {
      const int grow = i0 + wm * 64 + (rs >> 2) * 16 + lHi * 4 + (rs & 3);
      const int sidx = split * 2 + wn;
      pm[(size_t)sidx * NROWS + grow] = mm;
      ps[(size_t)sidx * NROWS + grow] = ss;
      pa[(size_t)sidx * NROWS + grow] = aa;
    }
  }
}

// ---------- Kernel 3: merge partials per row (32 blocks, 1 row/thread) ------
__global__ __launch_bounds__(256) void combine_partial(
    const float* __restrict__ pm, const float* __restrict__ ps,
    const int* __restrict__ pa, const float* __restrict__ diag,
    float* __restrict__ partL, float* __restrict__ partC) {
  const int i = blockIdx.x * 256 + threadIdx.x;   // NCOMB*256 == NROWS
  // pass 1: global max (and argmax with min-j ties)
  float mm = pm[i];
  int   aa = pa[i];
  #pragma unroll
  for (int s = 1; s < NPART; ++s) {
    float om = pm[(size_t)s * NROWS + i];
    int   oa = pa[(size_t)s * NROWS + i];
    if (om > mm || (om == mm && oa < aa)) { mm = om; aa = oa; }
  }
  // pass 2: sum of rescaled partial sums
  float ss = 0.f;
  #pragma unroll
  for (int s = 0; s < NPART; ++s)
    ss += ps[(size_t)s * NROWS + i] * __expf(pm[(size_t)s * NROWS + i] - mm);
  float lsum = (mm + logf(ss)) - diag[i];
  float csum = (aa == i) ? 1.0f : 0.0f;
  // block reduction
  #pragma unroll
  for (int d = 32; d; d >>= 1) {
    lsum += __shfl_xor(lsum, d);
    csum += __shfl_xor(csum, d);
  }
  __shared__ float wl[4], wc[4];
  int w = threadIdx.x >> 6;
  if ((threadIdx.x & 63) == 0) { wl[w] = lsum; wc[w] = csum; }
  __syncthreads();
  if (threadIdx.x == 0) {
    partL[blockIdx.x] = wl[0] + wl[1] + wl[2] + wl[3];
    partC[blockIdx.x] = wc[0] + wc[1] + wc[2] + wc[3];
  }
}

// ---------- Kernel 4: final scalars ----------
__global__ __launch_bounds__(64) void final_kernel(
    const float* __restrict__ partL, const float* __restrict__ partC,
    float* __restrict__ out) {
  int t = threadIdx.x;
  float l = (t < NCOMB) ? partL[t] : 0.f;
  float c = (t < NCOMB) ? partC[t] : 0.f;
  #pragma unroll
  for (int d = 32; d; d >>= 1) {
    l += __shfl_xor(l, d);
    c += __shfl_xor(c, d);
  }
  if (t == 0) {
    out[0] = l / (float)NROWS;
    out[1] = 100.f * c / (float)NROWS;
  }
}

extern "C" void kernel_launch(void* const* d_in, const int* in_sizes, int n_in,
                              void* d_out, int out_size, void* d_ws, size_t ws_size,
                              hipStream_t stream) {
  const float* x = (const float*)d_in[0];
  float* out = (float*)d_out;

  // workspace layout (~14.3 MB), 256B-aligned slices
  char* ws = (char*)d_ws;
  size_t off = 0;
  auto take = [&](size_t bytes) { void* p = ws + off; off += (bytes + 255) & ~(size_t)255; return p; };
  f16*   ph    = (f16*)take((size_t)NROWS * KSPL * sizeof(f16));
  f16*   ah    = (f16*)take((size_t)NROWS * KSPL * sizeof(f16));
  float* bvec  = (float*)take((size_t)NROWS * sizeof(float));
  float* pm    = (float*)take((size_t)NPART * NROWS * sizeof(float));
  float* ps    = (float*)take((size_t)NPART * NROWS * sizeof(float));
  int*   pa    = (int*)take((size_t)NPART * NROWS * sizeof(int));
  float* diag  = (float*)take((size_t)NROWS * sizeof(float));
  float* partL = (float*)take((size_t)NCOMB * sizeof(float));
  float* partC = (float*)take((size_t)NCOMB * sizeof(float));

  prep_kernel<<<dim3((NROWS * 64) / 256), 256, 0, stream>>>(x, ph, ah, bvec);
  main_kernel<<<dim3(NROWS / BM, NSPLIT), 256, 0, stream>>>(ph, ah, bvec, pm, ps, pa, diag);
  combine_partial<<<dim3(NCOMB), 256, 0, stream>>>(pm, ps, pa, diag, partL, partC);
  final_kernel<<<1, 64, 0, stream>>>(partL, partC, out);
}